// Round 10
// baseline (250.592 us; speedup 1.0000x reference)
//
#include <hip/hip_runtime.h>

#define GRAVITY_F 9.81f
#define VPT 4  // vertices per thread (inertia + pack kernels)

typedef int   v4i  __attribute__((ext_vector_type(4)));
typedef float v4f  __attribute__((ext_vector_type(4), aligned(4)));
typedef float v4fa __attribute__((ext_vector_type(4), aligned(16)));

// 11/11/10-bit fixed-point packing of (x,y,z) over [-6,6] into one uint32.
// packed array = 4 B/vertex = 2 MB total -> strictly L2-resident per XCD.
#define QLO  (-6.0f)
#define SXY  (2047.0f / 12.0f)
#define SZ   (1023.0f / 12.0f)
#define KXY  (12.0f / 2047.0f)
#define KZ   (12.0f / 1023.0f)

__device__ __forceinline__ unsigned int qxy(float x) {
    float t = (x - QLO) * SXY;
    t = fminf(fmaxf(t, 0.0f), 2047.0f);
    return (unsigned int)__float2int_rn(t);
}
__device__ __forceinline__ unsigned int qz(float x) {
    float t = (x - QLO) * SZ;
    t = fminf(fmaxf(t, 0.0f), 1023.0f);
    return (unsigned int)__float2int_rn(t);
}

__device__ __forceinline__ float blockReduceSum(float val) {
    #pragma unroll
    for (int off = 32; off > 0; off >>= 1)
        val += __shfl_down(val, off, 64);
    __shared__ float smem[16];
    const int lane = threadIdx.x & 63;
    const int wave = threadIdx.x >> 6;
    if (lane == 0) smem[wave] = val;
    __syncthreads();
    const int nwaves = (blockDim.x + 63) >> 6;
    val = 0.0f;
    if (wave == 0) {
        if (lane < nwaves) val = smem[lane];
        #pragma unroll
        for (int off = 8; off > 0; off >>= 1)
            val += __shfl_down(val, off, 64);
    }
    return val;  // valid on thread 0 only
}

// Pack pos_next -> 4-B quantized records, 4 vertices/thread, vectorized.
__global__ void pack_kernel(const float* __restrict__ pn,
                            unsigned int* __restrict__ out, int V) {
    const int t = blockIdx.x * blockDim.x + threadIdx.x;
    const int v0 = t * VPT;
    if (v0 + VPT <= V) {
        v4fa a = __builtin_nontemporal_load(((const v4fa*)pn) + 3 * t + 0);
        v4fa b = __builtin_nontemporal_load(((const v4fa*)pn) + 3 * t + 1);
        v4fa c = __builtin_nontemporal_load(((const v4fa*)pn) + 3 * t + 2);
        float f[12];
        *(v4fa*)(f + 0) = a; *(v4fa*)(f + 4) = b; *(v4fa*)(f + 8) = c;
        uint4 o;
        o.x = qxy(f[0]) | (qxy(f[1])  << 11) | (qz(f[2])  << 22);
        o.y = qxy(f[3]) | (qxy(f[4])  << 11) | (qz(f[5])  << 22);
        o.z = qxy(f[6]) | (qxy(f[7])  << 11) | (qz(f[8])  << 22);
        o.w = qxy(f[9]) | (qxy(f[10]) << 11) | (qz(f[11]) << 22);
        ((uint4*)out)[t] = o;
    } else {
        for (int v = v0; v < V; ++v) {
            out[v] = qxy(pn[3 * v + 0]) | (qxy(pn[3 * v + 1]) << 11)
                   | (qz(pn[3 * v + 2]) << 22);
        }
    }
}

__device__ __forceinline__ void dequant(unsigned int w, float* x) {
    x[0] = (float)(w & 2047u) * KXY + QLO;
    x[1] = (float)((w >> 11) & 2047u) * KXY + QLO;
    x[2] = (float)(w >> 22) * KZ + QLO;
}

// Blocks [0, Eblocks): element terms, 1 elem/thread (R8-best config).
// Blocks [Eblocks, ...): vertex terms, VPT vertices/thread (exact fp32).
// Streams nontemporal (R8 vs R9: nt = 69 us, cached = 79 us).
__global__ void
fused_kernel(const float* __restrict__ pn,
             const float* __restrict__ pc,
             const float* __restrict__ pp,
             const float* __restrict__ mass,
             const int*   __restrict__ elems,
             const float* __restrict__ vols,
             const float* __restrict__ rinv,
             const float* __restrict__ lam_p,
             const float* __restrict__ mu_p,
             const unsigned int* __restrict__ packedq,
             float* __restrict__ out,
             int V, int E, int Eblocks,
             float sI, float sG, float sS) {
    float local = 0.0f;

    if ((int)blockIdx.x < Eblocks) {
        const float lam = lam_p[0];
        const float mu  = mu_p[0];
        const int e = blockIdx.x * blockDim.x + threadIdx.x;
        const int  ec = e < E ? e : (E - 1);
        const float sc = e < E ? sS : 0.0f;

        const v4i idx  = __builtin_nontemporal_load(((const v4i*)elems) + ec);
        const float vol = __builtin_nontemporal_load(vols + ec);

        // Vertex gathers: 4 B each from the 2 MB L2-resident quantized copy
        const unsigned int g0 = packedq[idx.x];
        const unsigned int g1 = packedq[idx.y];
        const unsigned int g2 = packedq[idx.z];
        const unsigned int g3 = packedq[idx.w];

        // rest_inv: 9 floats as dwordx4 + dwordx4 + dword (nontemporal)
        const float* Rp = rinv + 9 * (size_t)ec;
        const v4f  ra = __builtin_nontemporal_load((const v4f*)(Rp + 0));
        const v4f  rb = __builtin_nontemporal_load((const v4f*)(Rp + 4));
        const float rc = __builtin_nontemporal_load(Rp + 8);
        float R[9] = {ra.x, ra.y, ra.z, ra.w, rb.x, rb.y, rb.z, rb.w, rc};

        float x[4][3];
        dequant(g0, x[0]);
        dequant(g1, x[1]);
        dequant(g2, x[2]);
        dequant(g3, x[3]);

        float d[3][3];
        #pragma unroll
        for (int r = 0; r < 3; ++r) {
            d[r][0] = x[1][r] - x[0][r];
            d[r][1] = x[2][r] - x[0][r];
            d[r][2] = x[3][r] - x[0][r];
        }
        float F[3][3];
        #pragma unroll
        for (int r = 0; r < 3; ++r)
            #pragma unroll
            for (int k = 0; k < 3; ++k)
                F[r][k] = d[r][0] * R[0 * 3 + k]
                        + d[r][1] * R[1 * 3 + k]
                        + d[r][2] * R[2 * 3 + k];
        const float det = F[0][0] * (F[1][1] * F[2][2] - F[1][2] * F[2][1])
                        - F[0][1] * (F[1][0] * F[2][2] - F[1][2] * F[2][0])
                        + F[0][2] * (F[1][0] * F[2][1] - F[1][1] * F[2][0]);
        const float ld = logf(fmaxf(det, 1e-8f));
        float tr = 0.0f;
        #pragma unroll
        for (int r = 0; r < 3; ++r)
            #pragma unroll
            for (int k = 0; k < 3; ++k)
                tr += F[r][k] * F[r][k];
        const float psi = 0.5f * lam * ld * ld - mu * ld + 0.5f * mu * (tr - 3.0f);
        local = sc * (psi * vol);
    } else {
        const int t = (blockIdx.x - Eblocks) * blockDim.x + threadIdx.x;
        const int v0 = t * VPT;
        if (v0 + VPT <= V) {
            v4fa n[3], c[3], q[3];
            #pragma unroll
            for (int k = 0; k < 3; ++k) {
                n[k] = __builtin_nontemporal_load(((const v4fa*)pn) + 3 * t + k);
                c[k] = __builtin_nontemporal_load(((const v4fa*)pc) + 3 * t + k);
                q[k] = __builtin_nontemporal_load(((const v4fa*)pp) + 3 * t + k);
            }
            const v4fa m4 = __builtin_nontemporal_load(((const v4fa*)mass) + t);
            const float* nf = (const float*)n;
            const float* cf = (const float*)c;
            const float* qf = (const float*)q;
            const float* mf = (const float*)&m4;
            #pragma unroll
            for (int j = 0; j < VPT; ++j) {
                const float m  = mf[j];
                const float y  = cf[3 * j + 1];
                const float a0 = nf[3 * j + 0] + qf[3 * j + 0] - 2.0f * cf[3 * j + 0];
                const float a1 = nf[3 * j + 1] + qf[3 * j + 1] - 2.0f * y;
                const float a2 = nf[3 * j + 2] + qf[3 * j + 2] - 2.0f * cf[3 * j + 2];
                local += sI * (m * (a0 * a0 + a1 * a1 + a2 * a2)) + sG * (m * y);
            }
        } else {
            for (int v = v0; v < V; ++v) {
                const float m  = mass[v];
                const float y  = pc[3 * v + 1];
                const float a0 = pn[3 * v + 0] + pp[3 * v + 0] - 2.0f * pc[3 * v + 0];
                const float a1 = pn[3 * v + 1] + pp[3 * v + 1] - 2.0f * y;
                const float a2 = pn[3 * v + 2] + pp[3 * v + 2] - 2.0f * pc[3 * v + 2];
                local += sI * (m * (a0 * a0 + a1 * a1 + a2 * a2)) + sG * (m * y);
            }
        }
    }

    const float tot = blockReduceSum(local);
    if (threadIdx.x == 0) atomicAdd(out, tot);  // device-scope, ~10k adds total
}

extern "C" void kernel_launch(void* const* d_in, const int* in_sizes, int n_in,
                              void* d_out, int out_size, void* d_ws, size_t ws_size,
                              hipStream_t stream) {
    const float* pos_next = (const float*)d_in[0];
    const float* pos_curr = (const float*)d_in[1];
    const float* pos_prev = (const float*)d_in[2];
    const float* mass     = (const float*)d_in[3];
    const int*   elements = (const int*)d_in[4];
    const float* rest_vol = (const float*)d_in[5];
    const float* rest_inv = (const float*)d_in[6];
    const float* lam_p    = (const float*)d_in[7];
    const float* mu_p     = (const float*)d_in[8];
    float* out = (float*)d_out;

    const int V = in_sizes[3];  // mass has V elements
    const int E = in_sizes[5];  // rest_volumes has E elements

    const float sI = 0.5f / (3.0f * (float)V);       // W_INERTIA * 0.5 / (3V)
    const float sG = -0.01f * GRAVITY_F / (float)V;  // W_GRAVITY * (-g) / V
    const float sS = 1.0f / (float)E;                // W_STRAIN / E

    const int block = 256;
    const int Eblocks = (E + block - 1) / block;
    const int Vblocks = (V + VPT * block - 1) / (VPT * block);
    const int grid = Eblocks + Vblocks;

    unsigned int* packedq = (unsigned int*)d_ws;  // V * 4 B = 2 MB

    hipMemsetAsync(out, 0, sizeof(float), stream);  // d_out is poisoned pre-call
    pack_kernel<<<(V / VPT + block - 1) / block + 1, block, 0, stream>>>(
        pos_next, packedq, V);
    fused_kernel<<<grid, block, 0, stream>>>(pos_next, pos_curr, pos_prev,
                                             mass, elements, rest_vol,
                                             rest_inv, lam_p, mu_p,
                                             packedq, out,
                                             V, E, Eblocks, sI, sG, sS);
}

// Round 12
// 207.659 us; speedup vs baseline: 1.2067x; 1.2067x over previous
//
#include <hip/hip_runtime.h>

#define GRAVITY_F 9.81f
#define VPT 4  // vertices per thread (inertia + pack kernels)

typedef int   v4i  __attribute__((ext_vector_type(4)));
typedef float v4f  __attribute__((ext_vector_type(4), aligned(4)));
typedef float v4fa __attribute__((ext_vector_type(4), aligned(16)));

// 11/11/10-bit fixed-point packing of (x,y,z) over [-6,6] into one uint32.
// packed array = 4 B/vertex = 2 MB total -> strictly L2-resident per XCD.
#define QLO  (-6.0f)
#define SXY  (2047.0f / 12.0f)
#define SZ   (1023.0f / 12.0f)
#define KXY  (12.0f / 2047.0f)
#define KZ   (12.0f / 1023.0f)

__device__ __forceinline__ unsigned int qxy(float x) {
    float t = (x - QLO) * SXY;
    t = fminf(fmaxf(t, 0.0f), 2047.0f);
    return (unsigned int)__float2int_rn(t);
}
__device__ __forceinline__ unsigned int qz(float x) {
    float t = (x - QLO) * SZ;
    t = fminf(fmaxf(t, 0.0f), 1023.0f);
    return (unsigned int)__float2int_rn(t);
}

__device__ __forceinline__ float blockReduceSum(float val) {
    #pragma unroll
    for (int off = 32; off > 0; off >>= 1)
        val += __shfl_down(val, off, 64);
    __shared__ float smem[16];
    const int lane = threadIdx.x & 63;
    const int wave = threadIdx.x >> 6;
    if (lane == 0) smem[wave] = val;
    __syncthreads();
    const int nwaves = (blockDim.x + 63) >> 6;
    val = 0.0f;
    if (wave == 0) {
        if (lane < nwaves) val = smem[lane];
        #pragma unroll
        for (int off = 8; off > 0; off >>= 1)
            val += __shfl_down(val, off, 64);
    }
    return val;  // valid on thread 0 only
}

// Pack pos_next -> 4-B quantized records, 4 vertices/thread, vectorized.
__global__ void pack_kernel(const float* __restrict__ pn,
                            unsigned int* __restrict__ out, int V) {
    const int t = blockIdx.x * blockDim.x + threadIdx.x;
    const int v0 = t * VPT;
    if (v0 + VPT <= V) {
        v4fa a = __builtin_nontemporal_load(((const v4fa*)pn) + 3 * t + 0);
        v4fa b = __builtin_nontemporal_load(((const v4fa*)pn) + 3 * t + 1);
        v4fa c = __builtin_nontemporal_load(((const v4fa*)pn) + 3 * t + 2);
        float f[12];
        *(v4fa*)(f + 0) = a; *(v4fa*)(f + 4) = b; *(v4fa*)(f + 8) = c;
        uint4 o;
        o.x = qxy(f[0]) | (qxy(f[1])  << 11) | (qz(f[2])  << 22);
        o.y = qxy(f[3]) | (qxy(f[4])  << 11) | (qz(f[5])  << 22);
        o.z = qxy(f[6]) | (qxy(f[7])  << 11) | (qz(f[8])  << 22);
        o.w = qxy(f[9]) | (qxy(f[10]) << 11) | (qz(f[11]) << 22);
        ((uint4*)out)[t] = o;
    } else {
        for (int v = v0; v < V; ++v) {
            out[v] = qxy(pn[3 * v + 0]) | (qxy(pn[3 * v + 1]) << 11)
                   | (qz(pn[3 * v + 2]) << 22);
        }
    }
}

__device__ __forceinline__ void dequant(unsigned int w, float* x) {
    x[0] = (float)(w & 2047u) * KXY + QLO;
    x[1] = (float)((w >> 11) & 2047u) * KXY + QLO;
    x[2] = (float)(w >> 22) * KZ + QLO;
}

// Blocks [0, Eblocks): element terms, 1 elem/thread (R8-best config).
// Blocks [Eblocks, ...): vertex terms, VPT vertices/thread (exact fp32).
// Streams nontemporal (R8 vs R9: nt = 69 us, cached = 79 us).
// Output: one partials slot per block (R10 showed single-address atomics
// from ~10k blocks serialize cross-XCD and cost ~48 us).
__global__ void
fused_kernel(const float* __restrict__ pn,
             const float* __restrict__ pc,
             const float* __restrict__ pp,
             const float* __restrict__ mass,
             const int*   __restrict__ elems,
             const float* __restrict__ vols,
             const float* __restrict__ rinv,
             const float* __restrict__ lam_p,
             const float* __restrict__ mu_p,
             const unsigned int* __restrict__ packedq,
             float* __restrict__ partials,
             int V, int E, int Eblocks,
             float sI, float sG, float sS) {
    float local = 0.0f;

    if ((int)blockIdx.x < Eblocks) {
        const float lam = lam_p[0];
        const float mu  = mu_p[0];
        const int e = blockIdx.x * blockDim.x + threadIdx.x;
        const int  ec = e < E ? e : (E - 1);
        const float sc = e < E ? sS : 0.0f;

        const v4i idx  = __builtin_nontemporal_load(((const v4i*)elems) + ec);
        const float vol = __builtin_nontemporal_load(vols + ec);

        // Vertex gathers: 4 B each from the 2 MB L2-resident quantized copy
        const unsigned int g0 = packedq[idx.x];
        const unsigned int g1 = packedq[idx.y];
        const unsigned int g2 = packedq[idx.z];
        const unsigned int g3 = packedq[idx.w];

        // rest_inv: 9 floats as dwordx4 + dwordx4 + dword (nontemporal)
        const float* Rp = rinv + 9 * (size_t)ec;
        const v4f  ra = __builtin_nontemporal_load((const v4f*)(Rp + 0));
        const v4f  rb = __builtin_nontemporal_load((const v4f*)(Rp + 4));
        const float rc = __builtin_nontemporal_load(Rp + 8);
        float R[9] = {ra.x, ra.y, ra.z, ra.w, rb.x, rb.y, rb.z, rb.w, rc};

        float x[4][3];
        dequant(g0, x[0]);
        dequant(g1, x[1]);
        dequant(g2, x[2]);
        dequant(g3, x[3]);

        float d[3][3];
        #pragma unroll
        for (int r = 0; r < 3; ++r) {
            d[r][0] = x[1][r] - x[0][r];
            d[r][1] = x[2][r] - x[0][r];
            d[r][2] = x[3][r] - x[0][r];
        }
        float F[3][3];
        #pragma unroll
        for (int r = 0; r < 3; ++r)
            #pragma unroll
            for (int k = 0; k < 3; ++k)
                F[r][k] = d[r][0] * R[0 * 3 + k]
                        + d[r][1] * R[1 * 3 + k]
                        + d[r][2] * R[2 * 3 + k];
        const float det = F[0][0] * (F[1][1] * F[2][2] - F[1][2] * F[2][1])
                        - F[0][1] * (F[1][0] * F[2][2] - F[1][2] * F[2][0])
                        + F[0][2] * (F[1][0] * F[2][1] - F[1][1] * F[2][0]);
        const float ld = logf(fmaxf(det, 1e-8f));
        float tr = 0.0f;
        #pragma unroll
        for (int r = 0; r < 3; ++r)
            #pragma unroll
            for (int k = 0; k < 3; ++k)
                tr += F[r][k] * F[r][k];
        const float psi = 0.5f * lam * ld * ld - mu * ld + 0.5f * mu * (tr - 3.0f);
        local = sc * (psi * vol);
    } else {
        const int t = (blockIdx.x - Eblocks) * blockDim.x + threadIdx.x;
        const int v0 = t * VPT;
        if (v0 + VPT <= V) {
            v4fa n[3], c[3], q[3];
            #pragma unroll
            for (int k = 0; k < 3; ++k) {
                n[k] = __builtin_nontemporal_load(((const v4fa*)pn) + 3 * t + k);
                c[k] = __builtin_nontemporal_load(((const v4fa*)pc) + 3 * t + k);
                q[k] = __builtin_nontemporal_load(((const v4fa*)pp) + 3 * t + k);
            }
            const v4fa m4 = __builtin_nontemporal_load(((const v4fa*)mass) + t);
            const float* nf = (const float*)n;
            const float* cf = (const float*)c;
            const float* qf = (const float*)q;
            const float* mf = (const float*)&m4;
            #pragma unroll
            for (int j = 0; j < VPT; ++j) {
                const float m  = mf[j];
                const float y  = cf[3 * j + 1];
                const float a0 = nf[3 * j + 0] + qf[3 * j + 0] - 2.0f * cf[3 * j + 0];
                const float a1 = nf[3 * j + 1] + qf[3 * j + 1] - 2.0f * y;
                const float a2 = nf[3 * j + 2] + qf[3 * j + 2] - 2.0f * cf[3 * j + 2];
                local += sI * (m * (a0 * a0 + a1 * a1 + a2 * a2)) + sG * (m * y);
            }
        } else {
            for (int v = v0; v < V; ++v) {
                const float m  = mass[v];
                const float y  = pc[3 * v + 1];
                const float a0 = pn[3 * v + 0] + pp[3 * v + 0] - 2.0f * pc[3 * v + 0];
                const float a1 = pn[3 * v + 1] + pp[3 * v + 1] - 2.0f * y;
                const float a2 = pn[3 * v + 2] + pp[3 * v + 2] - 2.0f * pc[3 * v + 2];
                local += sI * (m * (a0 * a0 + a1 * a1 + a2 * a2)) + sG * (m * y);
            }
        }
    }

    const float tot = blockReduceSum(local);
    if (threadIdx.x == 0) partials[blockIdx.x] = tot;
}

__global__ void reduce_kernel(const float* __restrict__ partials, int n,
                              float* __restrict__ out) {
    double s = 0.0;
    for (int i = threadIdx.x; i < n; i += blockDim.x)
        s += (double)partials[i];
    __shared__ double sm[256];
    sm[threadIdx.x] = s;
    __syncthreads();
    #pragma unroll
    for (int off = 128; off > 0; off >>= 1) {
        if (threadIdx.x < off) sm[threadIdx.x] += sm[threadIdx.x + off];
        __syncthreads();
    }
    if (threadIdx.x == 0) out[0] = (float)sm[0];
}

extern "C" void kernel_launch(void* const* d_in, const int* in_sizes, int n_in,
                              void* d_out, int out_size, void* d_ws, size_t ws_size,
                              hipStream_t stream) {
    const float* pos_next = (const float*)d_in[0];
    const float* pos_curr = (const float*)d_in[1];
    const float* pos_prev = (const float*)d_in[2];
    const float* mass     = (const float*)d_in[3];
    const int*   elements = (const int*)d_in[4];
    const float* rest_vol = (const float*)d_in[5];
    const float* rest_inv = (const float*)d_in[6];
    const float* lam_p    = (const float*)d_in[7];
    const float* mu_p     = (const float*)d_in[8];
    float* out = (float*)d_out;

    const int V = in_sizes[3];  // mass has V elements
    const int E = in_sizes[5];  // rest_volumes has E elements

    const float sI = 0.5f / (3.0f * (float)V);       // W_INERTIA * 0.5 / (3V)
    const float sG = -0.01f * GRAVITY_F / (float)V;  // W_GRAVITY * (-g) / V
    const float sS = 1.0f / (float)E;                // W_STRAIN / E

    const int block = 256;
    const int Eblocks = (E + block - 1) / block;
    const int Vblocks = (V + VPT * block - 1) / (VPT * block);
    const int grid = Eblocks + Vblocks;

    float* partials = (float*)d_ws;  // grid floats; every slot overwritten
    const size_t part_bytes = ((size_t)grid * sizeof(float) + 255) & ~(size_t)255;
    unsigned int* packedq = (unsigned int*)((char*)d_ws + part_bytes);  // 2 MB

    pack_kernel<<<(V / VPT + block - 1) / block + 1, block, 0, stream>>>(
        pos_next, packedq, V);
    fused_kernel<<<grid, block, 0, stream>>>(pos_next, pos_curr, pos_prev,
                                             mass, elements, rest_vol,
                                             rest_inv, lam_p, mu_p,
                                             packedq, partials,
                                             V, E, Eblocks, sI, sG, sS);
    reduce_kernel<<<1, 256, 0, stream>>>(partials, grid, out);
}